// Round 1
// baseline (64.810 us; speedup 1.0000x reference)
//
#include <hip/hip_runtime.h>

// Leapfrog KDK integrator, softened point-mass accel:
//   a(q) = -q / (r*(r+1)^2 + 1e-12)
// Reference: t_f = ts[N-1]+0.001; dt_i = (t_f - ts[i])/n_steps; 64 KDK steps.
// Output rows (2N x 6): row 2i = trail[i], row 2i+1 = lead[i].
//
// R2 change vs previous best (64.8 us):
//  - One thread integrates BOTH the lead and trail particle of index i,
//    packed component-wise into <2 x float> ext-vectors (.x=lead, .y=trail).
//    The two systems share ts[i]/dt and have identical op structure, so the
//    backend can emit v_pk_*_f32 (VOPP): ~1.8x fewer VALU issue slots.
//  - Per-system arithmetic (fmaf order, v_sqrt_f32/v_rcp_f32 approx) is
//    unchanged from the passing kernel -> same rounding, absmax ~0.031.
//  - Output rows 2i/2i+1 are now contiguous per thread: 3 aligned float4
//    stores; inputs as 3 aligned float2 loads per array.

#define N_PART 65536

typedef float f32x2 __attribute__((ext_vector_type(2)));

__device__ __forceinline__ f32x2 fma2(f32x2 a, f32x2 b, f32x2 c) {
#if __has_builtin(__builtin_elementwise_fma)
    return __builtin_elementwise_fma(a, b, c);
#else
    f32x2 r;
    r.x = fmaf(a.x, b.x, c.x);
    r.y = fmaf(a.y, b.y, c.y);
    return r;
#endif
}

// Returns -1 / (r*(r+1)^2 + 1e-12), element-wise for two systems.
__device__ __forceinline__ f32x2 neg_inv_denom2(f32x2 qx, f32x2 qy, f32x2 qz) {
    f32x2 r2 = fma2(qx, qx, fma2(qy, qy, qz * qz));
    f32x2 r;
    r.x = __builtin_amdgcn_sqrtf(r2.x);   // v_sqrt_f32, ~1 ulp, 0 -> 0
    r.y = __builtin_amdgcn_sqrtf(r2.y);
    const f32x2 one = {1.0f, 1.0f};
    const f32x2 eps = {1e-12f, 1e-12f};
    f32x2 rp = r + one;
    f32x2 d  = fma2(r * rp, rp, eps);
    f32x2 res;
    res.x = -__builtin_amdgcn_rcpf(d.x);  // v_rcp_f32, ~1 ulp
    res.y = -__builtin_amdgcn_rcpf(d.y);
    return res;
}

__global__ void __launch_bounds__(256)
leapfrog_pair_kernel(const float* __restrict__ ts,
                     const float* __restrict__ w0_lead,
                     const float* __restrict__ w0_trail,
                     const int* __restrict__ n_steps_p,
                     float* __restrict__ out) {
    const int i = blockIdx.x * blockDim.x + threadIdx.x;
    if (i >= N_PART) return;

    const float t_f     = ts[N_PART - 1] + 0.001f;  // uniform -> s_load
    const int   n_steps = *n_steps_p;
    const float dt      = (t_f - ts[i]) / (float)n_steps;

    const long b = (long)i * 6;   // rows are 24B, 8B-aligned -> float2 loads
    const float2 l0 = *reinterpret_cast<const float2*>(w0_lead + b);
    const float2 l1 = *reinterpret_cast<const float2*>(w0_lead + b + 2);
    const float2 l2 = *reinterpret_cast<const float2*>(w0_lead + b + 4);
    const float2 t0 = *reinterpret_cast<const float2*>(w0_trail + b);
    const float2 t1 = *reinterpret_cast<const float2*>(w0_trail + b + 2);
    const float2 t2 = *reinterpret_cast<const float2*>(w0_trail + b + 4);

    // .x = lead system, .y = trail system
    f32x2 qx = {l0.x, t0.x};
    f32x2 qy = {l0.y, t0.y};
    f32x2 qz = {l1.x, t1.x};
    f32x2 px = {l1.y, t1.y};
    f32x2 py = {l2.x, t2.x};
    f32x2 pz = {l2.y, t2.y};

    const f32x2 dt2  = {dt, dt};
    const f32x2 hdt2 = {0.5f * dt, 0.5f * dt};

    // Opening half kick: ph = p + hdt * a(q0)
    f32x2 c   = hdt2 * neg_inv_denom2(qx, qy, qz);
    f32x2 phx = fma2(c, qx, px);
    f32x2 phy = fma2(c, qy, py);
    f32x2 phz = fma2(c, qz, pz);

    // n_steps-1 full drift+kick pairs (folded half-kicks)
    #pragma unroll 4
    for (int s = 0; s < n_steps - 1; ++s) {
        qx = fma2(dt2, phx, qx);
        qy = fma2(dt2, phy, qy);
        qz = fma2(dt2, phz, qz);
        c  = dt2 * neg_inv_denom2(qx, qy, qz);
        phx = fma2(c, qx, phx);
        phy = fma2(c, qy, phy);
        phz = fma2(c, qz, phz);
    }

    // Final drift + closing half kick
    qx = fma2(dt2, phx, qx);
    qy = fma2(dt2, phy, qy);
    qz = fma2(dt2, phz, qz);
    c  = hdt2 * neg_inv_denom2(qx, qy, qz);
    px = fma2(c, qx, phx);
    py = fma2(c, qy, phy);
    pz = fma2(c, qz, phz);

    // Rows 2i (trail) and 2i+1 (lead) are contiguous: 48B, 16B-aligned.
    float4* o = reinterpret_cast<float4*>(out + (long)i * 12);
    o[0] = make_float4(qx.y, qy.y, qz.y, px.y);   // trail: q, px
    o[1] = make_float4(py.y, pz.y, qx.x, qy.x);   // trail: py,pz | lead: qx,qy
    o[2] = make_float4(qz.x, px.x, py.x, pz.x);   // lead: qz, p
}

extern "C" void kernel_launch(void* const* d_in, const int* in_sizes, int n_in,
                              void* d_out, int out_size, void* d_ws, size_t ws_size,
                              hipStream_t stream) {
    const float* ts       = (const float*)d_in[0];
    const float* w0_lead  = (const float*)d_in[1];
    const float* w0_trail = (const float*)d_in[2];
    const int*   n_steps  = (const int*)d_in[3];
    float* out = (float*)d_out;

    const int total = N_PART;                      // 65536 threads (one per pair)
    const int block = 256;
    const int grid  = (total + block - 1) / block; // 256 blocks = 1/CU

    leapfrog_pair_kernel<<<grid, block, 0, stream>>>(ts, w0_lead, w0_trail, n_steps, out);
}